// Round 16
// baseline (277.697 us; speedup 1.0000x reference)
//
#include <hip/hip_runtime.h>

typedef short  short8  __attribute__((ext_vector_type(8)));
typedef float  floatx4 __attribute__((ext_vector_type(4)));

#define TT 512
#define DD 32
#define HH 128
#define AA 10
#define LOG2E 1.44269504088896340736f

__device__ __forceinline__ unsigned f2bf(float f) {
    unsigned u = __builtin_bit_cast(unsigned, f);
    return (u + 0x7fffu + ((u >> 16) & 1u)) >> 16;   // RNE f32 -> bf16
}

__device__ __forceinline__ short8 cvt8(floatx4 a, floatx4 b) {
    short8 r;
    r[0] = (short)f2bf(a[0]); r[1] = (short)f2bf(a[1]);
    r[2] = (short)f2bf(a[2]); r[3] = (short)f2bf(a[3]);
    r[4] = (short)f2bf(b[0]); r[5] = (short)f2bf(b[1]);
    r[6] = (short)f2bf(b[2]); r[7] = (short)f2bf(b[3]);
    return r;
}

// activations on pre-scaled gates (scale folded into weights/bias)
__device__ __forceinline__ float sig2(float a) {   // a = -x*log2e
    return __builtin_amdgcn_rcpf(1.0f + __builtin_amdgcn_exp2f(a));
}
__device__ __forceinline__ float tanh2(float a) {  // a = 2x*log2e
    return 1.0f - 2.0f * __builtin_amdgcn_rcpf(1.0f + __builtin_amdgcn_exp2f(a));
}

// lgkm-only step barrier: x prefetch loads float across it
__device__ __forceinline__ void step_barrier() {
    asm volatile("s_waitcnt lgkmcnt(0)" ::: "memory");
    __builtin_amdgcn_s_barrier();
    asm volatile("" ::: "memory");
}

// Prepass: x (f32) -> bf16 in d_ws, same [B][T][D] layout.
__global__ __launch_bounds__(256)
void xcvt(const float* __restrict__ x, unsigned short* __restrict__ xb) {
    const long i = (long)blockIdx.x * 256 + threadIdx.x;
    floatx4 a = *(const floatx4*)(x + 8 * i);
    floatx4 b = *(const floatx4*)(x + 8 * i + 4);
    *(short8*)(xb + 8 * i) = cvt8(a, b);
}

// One block = 4 batch rows; 256 blocks = 1 per CU.
// R14 base + STATIC WAVE DE-PHASING: the two waves sharing a SIMD would
// otherwise hit their VALU-serial windows (EW issue, EW-B tail) in lockstep,
// leaving the matrix pipe idle.  Odd waves schedule next-step x-MFMAs at TOP
// of step (R12 order -> reach EW-B ~155cy earlier); even waves schedule them
// at BOTTOM, pre-barrier (R14 order).  The offset makes one wave's EW phase
// overlap the other's MFMA phase.  Wave-uniform branch, equal barrier count.
// h layout: addr(b,j) = b*256 + ((2j+32b)&255)  (rotation swizzle).
template<int USEWS>
__global__ __launch_bounds__(512, 2)
void lstm_fused(const float* __restrict__ x,    const unsigned short* __restrict__ xbf,
                const float* __restrict__ W_ih, const float* __restrict__ W_hh,
                const float* __restrict__ b_ih, const float* __restrict__ b_hh,
                const float* __restrict__ fc_w, const float* __restrict__ fc_b,
                float* __restrict__ out)
{
    __shared__ unsigned short h_lds[2][4 * HH];    // 2 KiB total, dbuf
    __shared__ float hq[4][HH + 4];

    const int tid  = threadIdx.x;
    const int lane = tid & 63;
    const int w    = tid >> 6;
    const int l15  = lane & 15;
    const int lgrp = lane >> 4;     // k-group 0..3
    const int bloc = l15 & 3;       // batch row of this lane's B-frag

    // ---- resident A-fragments (bf16, gate-scaled) + bias C-operands ----
    short8  afr[4][5];
    floatx4 biasv[4];
    #pragma unroll
    for (int tg = 0; tg < 4; ++tg) {
        const float sc = (tg == 2) ? (2.0f * LOG2E) : (-LOG2E);
        const int m  = w + 8 * tg;
        const int ga = 16 * m + l15;
        #pragma unroll
        for (int s = 0; s < 4; ++s) {
            const float* p = W_hh + ga * HH + 32 * s + 8 * lgrp;
            afr[tg][s] = cvt8(*(const floatx4*)p * sc, *(const floatx4*)(p + 4) * sc);
        }
        {
            const float* p = W_ih + ga * DD + 8 * lgrp;
            afr[tg][4] = cvt8(*(const floatx4*)p * sc, *(const floatx4*)(p + 4) * sc);
        }
        #pragma unroll
        for (int r = 0; r < 4; ++r) {
            const int gd = 16 * m + 4 * lgrp + r;
            biasv[tg][r] = (b_ih[gd] + b_hh[gd]) * sc;
        }
    }

    // zero both h buffers: exactly 512 dwords
    ((unsigned*)h_lds)[tid] = 0u;
    __syncthreads();

    // packed-lane mapping: quad element rs = l15>>2
    const int rs  = l15 >> 2;
    const bool sb0 = (rs & 1) != 0;
    const bool sb1 = (rs & 2) != 0;
    const int bp  = bloc;
    const int jp  = 16 * w + 4 * lgrp + rs;

    // hoisted LDS offsets (rotation swizzle)
    const int rb = bloc * 256;
    const int rdA0 = rb + ((  0 + 16 * lgrp + 32 * bloc) & 255);
    const int rdA1 = rb + (( 64 + 16 * lgrp + 32 * bloc) & 255);
    const int rdA2 = rb + ((128 + 16 * lgrp + 32 * bloc) & 255);
    const int rdA3 = rb + ((192 + 16 * lgrp + 32 * bloc) & 255);
    const int rdB0 = rdA0 + 1024, rdB1 = rdA1 + 1024, rdB2 = rdA2 + 1024, rdB3 = rdA3 + 1024;
    const int wrA = bp * 256 + ((2 * jp + 32 * bp) & 255);          // write buf0
    const int wrB = wrA + 1024;                                      // write buf1

    // x addressing: scalar base walks with t (uniform), lane offset invariant
    const size_t blkbase = (size_t)blockIdx.x * 4 * TT * DD;
    const int    xlane   = bloc * (TT * DD) + 8 * lgrp;    // elements
    const unsigned short* xsb = xbf + blkbase;             // USEWS base
    const float*          xfb = x   + blkbase;             // fallback base

    // ---- prologue: acc0 = bias + W_ih@x(0); xf1 = x(1) ----
    floatx4 acc0[4], acc1[4];
    short8  xf0, xf1;
    floatx4 xa0, xb0_, xa1, xb1_;
    if constexpr (USEWS) {
        short8 xc0 = *(const short8*)(xsb + xlane);               // x(0)
        #pragma unroll
        for (int tg = 0; tg < 4; ++tg)
            acc0[tg] = __builtin_amdgcn_mfma_f32_16x16x32_bf16(afr[tg][4], xc0, biasv[tg], 0, 0, 0);
        xf1 = *(const short8*)(xsb + DD + xlane);                 // x(1)
    } else {
        floatx4 a0 = *(const floatx4*)(xfb + xlane);
        floatx4 b0 = *(const floatx4*)(xfb + xlane + 4);
        short8 xc0 = cvt8(a0, b0);
        #pragma unroll
        for (int tg = 0; tg < 4; ++tg)
            acc0[tg] = __builtin_amdgcn_mfma_f32_16x16x32_bf16(afr[tg][4], xc0, biasv[tg], 0, 0, 0);
        xa1  = *(const floatx4*)(xfb + DD + xlane);
        xb1_ = *(const floatx4*)(xfb + DD + xlane + 4);
    }

    float cval = 0.f, hval = 0.f;
    const char* lb = (const char*)h_lds;

    // ---- shared EW pieces ----
    auto HMFMA_IF = [&](floatx4 (&accP)[4], short8 hb0, short8 hb1, short8 hb2, short8 hb3) {
        accP[0] = __builtin_amdgcn_mfma_f32_16x16x32_bf16(afr[0][0], hb0, accP[0], 0, 0, 0);
        accP[0] = __builtin_amdgcn_mfma_f32_16x16x32_bf16(afr[0][1], hb1, accP[0], 0, 0, 0);
        accP[0] = __builtin_amdgcn_mfma_f32_16x16x32_bf16(afr[0][2], hb2, accP[0], 0, 0, 0);
        accP[0] = __builtin_amdgcn_mfma_f32_16x16x32_bf16(afr[0][3], hb3, accP[0], 0, 0, 0);
        accP[1] = __builtin_amdgcn_mfma_f32_16x16x32_bf16(afr[1][0], hb0, accP[1], 0, 0, 0);
        accP[1] = __builtin_amdgcn_mfma_f32_16x16x32_bf16(afr[1][1], hb1, accP[1], 0, 0, 0);
        accP[1] = __builtin_amdgcn_mfma_f32_16x16x32_bf16(afr[1][2], hb2, accP[1], 0, 0, 0);
        accP[1] = __builtin_amdgcn_mfma_f32_16x16x32_bf16(afr[1][3], hb3, accP[1], 0, 0, 0);
    };
    auto HMFMA_GO = [&](floatx4 (&accP)[4], short8 hb0, short8 hb1, short8 hb2, short8 hb3) {
        accP[2] = __builtin_amdgcn_mfma_f32_16x16x32_bf16(afr[2][0], hb0, accP[2], 0, 0, 0);
        accP[2] = __builtin_amdgcn_mfma_f32_16x16x32_bf16(afr[2][1], hb1, accP[2], 0, 0, 0);
        accP[2] = __builtin_amdgcn_mfma_f32_16x16x32_bf16(afr[2][2], hb2, accP[2], 0, 0, 0);
        accP[2] = __builtin_amdgcn_mfma_f32_16x16x32_bf16(afr[2][3], hb3, accP[2], 0, 0, 0);
        accP[3] = __builtin_amdgcn_mfma_f32_16x16x32_bf16(afr[3][0], hb0, accP[3], 0, 0, 0);
        accP[3] = __builtin_amdgcn_mfma_f32_16x16x32_bf16(afr[3][1], hb1, accP[3], 0, 0, 0);
        accP[3] = __builtin_amdgcn_mfma_f32_16x16x32_bf16(afr[3][2], hb2, accP[3], 0, 0, 0);
        accP[3] = __builtin_amdgcn_mfma_f32_16x16x32_bf16(afr[3][3], hb3, accP[3], 0, 0, 0);
    };
    auto EWA = [&](floatx4 (&accP)[4], float& iv, float& fv, float& t1) {
        const float v01 = sb0 ? accP[0][1] : accP[0][0];
        const float v23 = sb0 ? accP[0][3] : accP[0][2];
        const float gi  = sb1 ? v23 : v01;
        const float u01 = sb0 ? accP[1][1] : accP[1][0];
        const float u23 = sb0 ? accP[1][3] : accP[1][2];
        const float gf  = sb1 ? u23 : u01;
        iv = sig2(gi);
        fv = sig2(gf);
        t1 = fv * cval;
    };
    auto EWB = [&](floatx4 (&accP)[4], float iv, float t1, int wro) {
        const float v01 = sb0 ? accP[2][1] : accP[2][0];
        const float v23 = sb0 ? accP[2][3] : accP[2][2];
        const float gg  = sb1 ? v23 : v01;
        const float gv  = tanh2(gg);
        cval = fmaf(iv, gv, t1);
        const float w01 = sb0 ? accP[3][1] : accP[3][0];
        const float w23 = sb0 ? accP[3][3] : accP[3][2];
        const float go  = sb1 ? w23 : w01;
        const float ov  = sig2(go);
        hval = ov * tanh2(cval * (2.0f * LOG2E));
        unsigned hp;
        asm("v_cvt_pk_bf16_f32 %0, %1, %2" : "=v"(hp) : "v"(hval), "v"(hval));
        *(unsigned short*)((char*)h_lds + wro) = (unsigned short)hp;
    };
    auto XMFMA = [&](floatx4 (&accN)[4], short8& xN, floatx4& xNa, floatx4& xNb) {
        short8 xc;
        if constexpr (USEWS) xc = xN; else xc = cvt8(xNa, xNb);
        #pragma unroll
        for (int tg = 0; tg < 4; ++tg)
            accN[tg] = __builtin_amdgcn_mfma_f32_16x16x32_bf16(afr[tg][4], xc, biasv[tg], 0, 0, 0);
    };
    auto XPREF = [&](short8& xL, floatx4& xLa, floatx4& xLb, int t) {
        const int tn = (t + 2 < TT) ? (t + 2) : (TT - 1);
        if constexpr (USEWS) {
            xL = *(const short8*)(xsb + (size_t)tn * DD + xlane);
        } else {
            xLa = *(const floatx4*)(xfb + (size_t)tn * DD + xlane);
            xLb = *(const floatx4*)(xfb + (size_t)tn * DD + xlane + 4);
        }
    };

    // BOT variant (R14): x-MFMAs at end of step, pre-barrier
    auto STEP_BOT = [&](floatx4 (&accP)[4], floatx4 (&accN)[4],
                        short8& xN, floatx4& xNa, floatx4& xNb,
                        short8& xL, floatx4& xLa, floatx4& xLb,
                        int r0, int r1, int r2, int r3, int wro, int t) {
        short8 hb0 = *(const short8*)(lb + r0);
        short8 hb1 = *(const short8*)(lb + r1);
        short8 hb2 = *(const short8*)(lb + r2);
        short8 hb3 = *(const short8*)(lb + r3);
        HMFMA_IF(accP, hb0, hb1, hb2, hb3);
        float iv, fv, t1;
        EWA(accP, iv, fv, t1);
        __builtin_amdgcn_sched_barrier(0);
        HMFMA_GO(accP, hb0, hb1, hb2, hb3);
        EWB(accP, iv, t1, wro);
        __builtin_amdgcn_sched_barrier(0);
        XMFMA(accN, xN, xNa, xNb);
        XPREF(xL, xLa, xLb, t);
        step_barrier();
    };

    // TOP variant (R12): x-MFMAs at start of step, post-barrier
    auto STEP_TOP = [&](floatx4 (&accP)[4], floatx4 (&accN)[4],
                        short8& xN, floatx4& xNa, floatx4& xNb,
                        short8& xL, floatx4& xLa, floatx4& xLb,
                        int r0, int r1, int r2, int r3, int wro, int t) {
        short8 hb0 = *(const short8*)(lb + r0);
        short8 hb1 = *(const short8*)(lb + r1);
        short8 hb2 = *(const short8*)(lb + r2);
        short8 hb3 = *(const short8*)(lb + r3);
        XMFMA(accN, xN, xNa, xNb);
        XPREF(xL, xLa, xLb, t);
        HMFMA_IF(accP, hb0, hb1, hb2, hb3);
        float iv, fv, t1;
        EWA(accP, iv, fv, t1);
        __builtin_amdgcn_sched_barrier(0);
        HMFMA_GO(accP, hb0, hb1, hb2, hb3);
        EWB(accP, iv, t1, wro);
        step_barrier();
    };

    if (w & 1) {
        #pragma unroll 1
        for (int t = 0; t < TT; t += 2) {
            STEP_TOP(acc0, acc1, xf1, xa1, xb1_, xf0, xa0, xb0_,
                     rdA0, rdA1, rdA2, rdA3, wrB, t);
            STEP_TOP(acc1, acc0, xf0, xa0, xb0_, xf1, xa1, xb1_,
                     rdB0, rdB1, rdB2, rdB3, wrA, t + 1);
        }
    } else {
        #pragma unroll 1
        for (int t = 0; t < TT; t += 2) {
            STEP_BOT(acc0, acc1, xf1, xa1, xb1_, xf0, xa0, xb0_,
                     rdA0, rdA1, rdA2, rdA3, wrB, t);
            STEP_BOT(acc1, acc0, xf0, xa0, xb0_, xf1, xa1, xb1_,
                     rdB0, rdB1, rdB2, rdB3, wrA, t + 1);
        }
    }

    // ---- epilogue: h_n, c_n, q = h @ fc_w^T + fc_b ----
    {
        const long bg = (long)blockIdx.x * 4 + bp;
        out[10240 + bg * HH + jp]          = hval;   // h_n
        out[10240 + 131072 + bg * HH + jp] = cval;   // c_n
        hq[bp][jp] = hval;
    }
    __syncthreads();
    if (tid < 4 * AA) {
        const int b = tid / AA, a = tid - AA * b;
        float s = fc_b[a];
        const float* fw = fc_w + a * HH;
        const float* hr = &hq[b][0];
        #pragma unroll 8
        for (int j = 0; j < HH; ++j) s = fmaf(hr[j], fw[j], s);
        out[((long)blockIdx.x * 4 + b) * AA + a] = s;
    }
}

extern "C" void kernel_launch(void* const* d_in, const int* in_sizes, int n_in,
                              void* d_out, int out_size, void* d_ws, size_t ws_size,
                              hipStream_t stream) {
    const float* x    = (const float*)d_in[0];
    const float* W_ih = (const float*)d_in[1];
    const float* W_hh = (const float*)d_in[2];
    const float* b_ih = (const float*)d_in[3];
    const float* b_hh = (const float*)d_in[4];
    const float* fc_w = (const float*)d_in[5];
    const float* fc_b = (const float*)d_in[6];
    float* out = (float*)d_out;

    const size_t xelems = (size_t)1024 * TT * DD;       // 16.78M
    if (ws_size >= xelems * sizeof(unsigned short)) {
        unsigned short* xb = (unsigned short*)d_ws;
        xcvt<<<dim3(8192), dim3(256), 0, stream>>>(x, xb);
        lstm_fused<1><<<dim3(256), dim3(512), 0, stream>>>(
            x, xb, W_ih, W_hh, b_ih, b_hh, fc_w, fc_b, out);
    } else {
        lstm_fused<0><<<dim3(256), dim3(512), 0, stream>>>(
            x, nullptr, W_ih, W_hh, b_ih, b_hh, fc_w, fc_b, out);
    }
}

// Round 17
// 268.136 us; speedup vs baseline: 1.0357x; 1.0357x over previous
//
#include <hip/hip_runtime.h>

typedef short  short8  __attribute__((ext_vector_type(8)));
typedef float  floatx4 __attribute__((ext_vector_type(4)));

#define TT 512
#define DD 32
#define HH 128
#define AA 10
#define LOG2E 1.44269504088896340736f

__device__ __forceinline__ unsigned f2bf(float f) {
    unsigned u = __builtin_bit_cast(unsigned, f);
    return (u + 0x7fffu + ((u >> 16) & 1u)) >> 16;   // RNE f32 -> bf16
}

__device__ __forceinline__ short8 cvt8(floatx4 a, floatx4 b) {
    short8 r;
    r[0] = (short)f2bf(a[0]); r[1] = (short)f2bf(a[1]);
    r[2] = (short)f2bf(a[2]); r[3] = (short)f2bf(a[3]);
    r[4] = (short)f2bf(b[0]); r[5] = (short)f2bf(b[1]);
    r[6] = (short)f2bf(b[2]); r[7] = (short)f2bf(b[3]);
    return r;
}

// activations on pre-scaled gates (scale folded into weights/bias)
__device__ __forceinline__ float sig2(float a) {   // a = -x*log2e
    return __builtin_amdgcn_rcpf(1.0f + __builtin_amdgcn_exp2f(a));
}
__device__ __forceinline__ float tanh2(float a) {  // a = 2x*log2e
    return 1.0f - 2.0f * __builtin_amdgcn_rcpf(1.0f + __builtin_amdgcn_exp2f(a));
}

// lgkm-only step barrier: x prefetch loads float across it
__device__ __forceinline__ void step_barrier() {
    asm volatile("s_waitcnt lgkmcnt(0)" ::: "memory");
    __builtin_amdgcn_s_barrier();
    asm volatile("" ::: "memory");
}

// Prepass: x (f32) -> bf16 in d_ws, same [B][T][D] layout.
__global__ __launch_bounds__(256)
void xcvt(const float* __restrict__ x, unsigned short* __restrict__ xb) {
    const long i = (long)blockIdx.x * 256 + threadIdx.x;
    floatx4 a = *(const floatx4*)(x + 8 * i);
    floatx4 b = *(const floatx4*)(x + 8 * i + 4);
    *(short8*)(xb + 8 * i) = cvt8(a, b);
}

// One block = 4 batch rows; 256 blocks = 1 per CU.  (R14 -- session best.)
// Step: ds_read h(t) | i,f chains | EW-A (hidden under g,o) | g,o chains |
// EW-B + ds_write | next-step x-MFMAs (pre-barrier: drain through the
// {lgkm, s_barrier, next ds_read} window on the matrix pipe) | barrier.
// Measured at issue saturation: MfmaUtil + VALUBusy ~= 100%.
// h layout: addr(b,j) = b*256 + ((2j+32b)&255)  (rotation swizzle, ~0 confl).
template<int USEWS>
__global__ __launch_bounds__(512, 2)
void lstm_fused(const float* __restrict__ x,    const unsigned short* __restrict__ xbf,
                const float* __restrict__ W_ih, const float* __restrict__ W_hh,
                const float* __restrict__ b_ih, const float* __restrict__ b_hh,
                const float* __restrict__ fc_w, const float* __restrict__ fc_b,
                float* __restrict__ out)
{
    __shared__ unsigned short h_lds[2][4 * HH];    // 2 KiB total, dbuf
    __shared__ float hq[4][HH + 4];

    const int tid  = threadIdx.x;
    const int lane = tid & 63;
    const int w    = tid >> 6;
    const int l15  = lane & 15;
    const int lgrp = lane >> 4;     // k-group 0..3
    const int bloc = l15 & 3;       // batch row of this lane's B-frag

    // ---- resident A-fragments (bf16, gate-scaled) + bias C-operands ----
    short8  afr[4][5];
    floatx4 biasv[4];
    #pragma unroll
    for (int tg = 0; tg < 4; ++tg) {
        const float sc = (tg == 2) ? (2.0f * LOG2E) : (-LOG2E);
        const int m  = w + 8 * tg;
        const int ga = 16 * m + l15;
        #pragma unroll
        for (int s = 0; s < 4; ++s) {
            const float* p = W_hh + ga * HH + 32 * s + 8 * lgrp;
            afr[tg][s] = cvt8(*(const floatx4*)p * sc, *(const floatx4*)(p + 4) * sc);
        }
        {
            const float* p = W_ih + ga * DD + 8 * lgrp;
            afr[tg][4] = cvt8(*(const floatx4*)p * sc, *(const floatx4*)(p + 4) * sc);
        }
        #pragma unroll
        for (int r = 0; r < 4; ++r) {
            const int gd = 16 * m + 4 * lgrp + r;
            biasv[tg][r] = (b_ih[gd] + b_hh[gd]) * sc;
        }
    }

    // zero both h buffers: exactly 512 dwords
    ((unsigned*)h_lds)[tid] = 0u;
    __syncthreads();

    // packed-lane mapping: quad element rs = l15>>2
    const int rs  = l15 >> 2;
    const bool sb0 = (rs & 1) != 0;
    const bool sb1 = (rs & 2) != 0;
    const int bp  = bloc;
    const int jp  = 16 * w + 4 * lgrp + rs;

    // hoisted LDS offsets (rotation swizzle)
    const int rb = bloc * 256;
    const int rdA0 = rb + ((  0 + 16 * lgrp + 32 * bloc) & 255);
    const int rdA1 = rb + (( 64 + 16 * lgrp + 32 * bloc) & 255);
    const int rdA2 = rb + ((128 + 16 * lgrp + 32 * bloc) & 255);
    const int rdA3 = rb + ((192 + 16 * lgrp + 32 * bloc) & 255);
    const int rdB0 = rdA0 + 1024, rdB1 = rdA1 + 1024, rdB2 = rdA2 + 1024, rdB3 = rdA3 + 1024;
    const int wrA = bp * 256 + ((2 * jp + 32 * bp) & 255);          // write buf0
    const int wrB = wrA + 1024;                                      // write buf1

    // x addressing: scalar base walks with t (uniform), lane offset invariant
    const size_t blkbase = (size_t)blockIdx.x * 4 * TT * DD;
    const int    xlane   = bloc * (TT * DD) + 8 * lgrp;    // elements
    const unsigned short* xsb = xbf + blkbase;             // USEWS base
    const float*          xfb = x   + blkbase;             // fallback base

    // ---- prologue: acc0 = bias + W_ih@x(0); xf1 = x(1) ----
    floatx4 acc0[4], acc1[4];
    short8  xf0, xf1;
    floatx4 xa0, xb0_, xa1, xb1_;
    if constexpr (USEWS) {
        short8 xc0 = *(const short8*)(xsb + xlane);               // x(0)
        #pragma unroll
        for (int tg = 0; tg < 4; ++tg)
            acc0[tg] = __builtin_amdgcn_mfma_f32_16x16x32_bf16(afr[tg][4], xc0, biasv[tg], 0, 0, 0);
        xf1 = *(const short8*)(xsb + DD + xlane);                 // x(1)
    } else {
        floatx4 a0 = *(const floatx4*)(xfb + xlane);
        floatx4 b0 = *(const floatx4*)(xfb + xlane + 4);
        short8 xc0 = cvt8(a0, b0);
        #pragma unroll
        for (int tg = 0; tg < 4; ++tg)
            acc0[tg] = __builtin_amdgcn_mfma_f32_16x16x32_bf16(afr[tg][4], xc0, biasv[tg], 0, 0, 0);
        xa1  = *(const floatx4*)(xfb + DD + xlane);
        xb1_ = *(const floatx4*)(xfb + DD + xlane + 4);
    }

    float cval = 0.f, hval = 0.f;
    const char* lb = (const char*)h_lds;

    // STEP(t): ds_read h(t) | i,f chains | EW-A | g,o chains | EW-B + write
    // | x-MFMAs for t+1 (pre-barrier, drain through barrier window) | barrier
    auto STEP = [&](floatx4 (&accP)[4], floatx4 (&accN)[4],
                    short8& xN, floatx4& xNa, floatx4& xNb,
                    short8& xL, floatx4& xLa, floatx4& xLb,
                    int r0, int r1, int r2, int r3, int wro, int t) {
        // h fragment reads (latency covered by prev step's pre-barrier x-MFMAs)
        short8 hb0 = *(const short8*)(lb + r0);
        short8 hb1 = *(const short8*)(lb + r1);
        short8 hb2 = *(const short8*)(lb + r2);
        short8 hb3 = *(const short8*)(lb + r3);

        // i-chain (tg=0), f-chain (tg=1)
        accP[0] = __builtin_amdgcn_mfma_f32_16x16x32_bf16(afr[0][0], hb0, accP[0], 0, 0, 0);
        accP[0] = __builtin_amdgcn_mfma_f32_16x16x32_bf16(afr[0][1], hb1, accP[0], 0, 0, 0);
        accP[0] = __builtin_amdgcn_mfma_f32_16x16x32_bf16(afr[0][2], hb2, accP[0], 0, 0, 0);
        accP[0] = __builtin_amdgcn_mfma_f32_16x16x32_bf16(afr[0][3], hb3, accP[0], 0, 0, 0);
        accP[1] = __builtin_amdgcn_mfma_f32_16x16x32_bf16(afr[1][0], hb0, accP[1], 0, 0, 0);
        accP[1] = __builtin_amdgcn_mfma_f32_16x16x32_bf16(afr[1][1], hb1, accP[1], 0, 0, 0);
        accP[1] = __builtin_amdgcn_mfma_f32_16x16x32_bf16(afr[1][2], hb2, accP[1], 0, 0, 0);
        accP[1] = __builtin_amdgcn_mfma_f32_16x16x32_bf16(afr[1][3], hb3, accP[1], 0, 0, 0);

        // EW-A: iv, fv, t1 (issues while g/o chains feed the pipe)
        float iv, fv, t1;
        {
            const float v01 = sb0 ? accP[0][1] : accP[0][0];
            const float v23 = sb0 ? accP[0][3] : accP[0][2];
            const float gi  = sb1 ? v23 : v01;
            const float u01 = sb0 ? accP[1][1] : accP[1][0];
            const float u23 = sb0 ? accP[1][3] : accP[1][2];
            const float gf  = sb1 ? u23 : u01;
            iv = sig2(gi);
            fv = sig2(gf);
            t1 = fv * cval;
        }
        __builtin_amdgcn_sched_barrier(0);

        // g-chain (tg=2), o-chain (tg=3)
        accP[2] = __builtin_amdgcn_mfma_f32_16x16x32_bf16(afr[2][0], hb0, accP[2], 0, 0, 0);
        accP[2] = __builtin_amdgcn_mfma_f32_16x16x32_bf16(afr[2][1], hb1, accP[2], 0, 0, 0);
        accP[2] = __builtin_amdgcn_mfma_f32_16x16x32_bf16(afr[2][2], hb2, accP[2], 0, 0, 0);
        accP[2] = __builtin_amdgcn_mfma_f32_16x16x32_bf16(afr[2][3], hb3, accP[2], 0, 0, 0);
        accP[3] = __builtin_amdgcn_mfma_f32_16x16x32_bf16(afr[3][0], hb0, accP[3], 0, 0, 0);
        accP[3] = __builtin_amdgcn_mfma_f32_16x16x32_bf16(afr[3][1], hb1, accP[3], 0, 0, 0);
        accP[3] = __builtin_amdgcn_mfma_f32_16x16x32_bf16(afr[3][2], hb2, accP[3], 0, 0, 0);
        accP[3] = __builtin_amdgcn_mfma_f32_16x16x32_bf16(afr[3][3], hb3, accP[3], 0, 0, 0);

        // EW-B: gv -> cval; ov; hval -> cvt_pk -> ds_write
        {
            const float v01 = sb0 ? accP[2][1] : accP[2][0];
            const float v23 = sb0 ? accP[2][3] : accP[2][2];
            const float gg  = sb1 ? v23 : v01;
            const float gv  = tanh2(gg);
            cval = fmaf(iv, gv, t1);
            const float w01 = sb0 ? accP[3][1] : accP[3][0];
            const float w23 = sb0 ? accP[3][3] : accP[3][2];
            const float go  = sb1 ? w23 : w01;
            const float ov  = sig2(go);
            hval = ov * tanh2(cval * (2.0f * LOG2E));
        }
        unsigned hp;
        asm("v_cvt_pk_bf16_f32 %0, %1, %2" : "=v"(hp) : "v"(hval), "v"(hval));
        *(unsigned short*)((char*)h_lds + wro) = (unsigned short)hp;
        __builtin_amdgcn_sched_barrier(0);

        // x-MFMAs for NEXT step -- pre-barrier: drain through the
        // {lgkm, s_barrier, next ds_read} window on the matrix pipe
        short8 xc;
        if constexpr (USEWS) xc = xN; else xc = cvt8(xNa, xNb);
        #pragma unroll
        for (int tg = 0; tg < 4; ++tg)
            accN[tg] = __builtin_amdgcn_mfma_f32_16x16x32_bf16(afr[tg][4], xc, biasv[tg], 0, 0, 0);

        // prefetch x(t+2) (floats across the barrier)
        const int tn = (t + 2 < TT) ? (t + 2) : (TT - 1);
        if constexpr (USEWS) {
            xL = *(const short8*)(xsb + (size_t)tn * DD + xlane);
        } else {
            xLa = *(const floatx4*)(xfb + (size_t)tn * DD + xlane);
            xLb = *(const floatx4*)(xfb + (size_t)tn * DD + xlane + 4);
        }

        step_barrier();
    };

    #pragma unroll 1
    for (int t = 0; t < TT; t += 2) {
        STEP(acc0, acc1, xf1, xa1, xb1_, xf0, xa0, xb0_,
             rdA0, rdA1, rdA2, rdA3, wrB, t);
        STEP(acc1, acc0, xf0, xa0, xb0_, xf1, xa1, xb1_,
             rdB0, rdB1, rdB2, rdB3, wrA, t + 1);
    }

    // ---- epilogue: h_n, c_n, q = h @ fc_w^T + fc_b ----
    {
        const long bg = (long)blockIdx.x * 4 + bp;
        out[10240 + bg * HH + jp]          = hval;   // h_n
        out[10240 + 131072 + bg * HH + jp] = cval;   // c_n
        hq[bp][jp] = hval;
    }
    __syncthreads();
    if (tid < 4 * AA) {
        const int b = tid / AA, a = tid - AA * b;
        float s = fc_b[a];
        const float* fw = fc_w + a * HH;
        const float* hr = &hq[b][0];
        #pragma unroll 8
        for (int j = 0; j < HH; ++j) s = fmaf(hr[j], fw[j], s);
        out[((long)blockIdx.x * 4 + b) * AA + a] = s;
    }
}

extern "C" void kernel_launch(void* const* d_in, const int* in_sizes, int n_in,
                              void* d_out, int out_size, void* d_ws, size_t ws_size,
                              hipStream_t stream) {
    const float* x    = (const float*)d_in[0];
    const float* W_ih = (const float*)d_in[1];
    const float* W_hh = (const float*)d_in[2];
    const float* b_ih = (const float*)d_in[3];
    const float* b_hh = (const float*)d_in[4];
    const float* fc_w = (const float*)d_in[5];
    const float* fc_b = (const float*)d_in[6];
    float* out = (float*)d_out;

    const size_t xelems = (size_t)1024 * TT * DD;       // 16.78M
    if (ws_size >= xelems * sizeof(unsigned short)) {
        unsigned short* xb = (unsigned short*)d_ws;
        xcvt<<<dim3(8192), dim3(256), 0, stream>>>(x, xb);
        lstm_fused<1><<<dim3(256), dim3(512), 0, stream>>>(
            x, xb, W_ih, W_hh, b_ih, b_hh, fc_w, fc_b, out);
    } else {
        lstm_fused<0><<<dim3(256), dim3(512), 0, stream>>>(
            x, nullptr, W_ih, W_hh, b_ih, b_hh, fc_w, fc_b, out);
    }
}